// Round 3
// baseline (5668.570 us; speedup 1.0000x reference)
//
#include <hip/hip_runtime.h>
#include <hip/hip_bf16.h>
#include <math.h>

#define S_LEN 4096
#define D_EMB 300
#define NG    600     // 4*HU
#define HDIM  300     // H
#define H2    600     // 2*H
#define VOCAB 100000

typedef float v4f __attribute__((ext_vector_type(4)));

__device__ __forceinline__ float bf2f(unsigned short u) {
  union { unsigned int i; float f; } v; v.i = ((unsigned int)u) << 16; return v.f;
}
__device__ __forceinline__ unsigned short f2bf(float f) {
  union { float f; unsigned int i; } v; v.f = f;
  return (unsigned short)((v.i + 0x7FFFu + ((v.i >> 16) & 1u)) >> 16);
}

__global__ void zero_hh(float* __restrict__ HH) {
  if (threadIdx.x < 640) HH[threadIdx.x] = 0.f;
}

__global__ void zero_out_f(float* __restrict__ o, int n) {
  if ((int)threadIdx.x < n) o[threadIdx.x] = 0.f;
}

// ---- GEMM: C[M,N](bf16) = gather(A)[M,K] @ B[K,N](f32) + bias(f32) -----------
// A dtype selected by template: f32 (embedding gather) or bf16 (hidden).
#define BM 64
#define BN 64
#define BK 16
template<bool A_BF16>
__global__ __launch_bounds__(256) void gemm_bias(
    const void* __restrict__ Av,
    const int* __restrict__ idx, int lda, int nrowsA,
    const float* __restrict__ B,
    const float* __restrict__ bias,
    unsigned short* __restrict__ C,
    int N, int K)
{
  __shared__ __align__(16) float As[BK][BM + 4];
  __shared__ __align__(16) float Bs[BK][BN + 4];
  __shared__ int rowidx[BM];

  int tid = threadIdx.x;
  int bm0 = blockIdx.y * BM, bn0 = blockIdx.x * BN;
  if (tid < BM) {
    int r = idx ? idx[bm0 + tid] : (bm0 + tid);
    r = (r < 0) ? 0 : ((r >= nrowsA) ? (nrowsA - 1) : r);   // clamp (no-op if valid)
    rowidx[tid] = r;
  }
  __syncthreads();

  int tx  = tid & 15, ty = tid >> 4;
  int ar  = tid >> 2, akv = (tid & 3) << 2;
  int bkr = tid >> 4, bnv = (tid & 15) << 2;

  float acc[4][4] = {};
  for (int kk = 0; kk < K; kk += BK) {
    float a0=0.f, a1=0.f, a2=0.f, a3=0.f;
    int ka = kk + akv;
    if (ka < K) {  // K % 4 == 0 -> whole quad in bounds
      if (A_BF16) {
        const unsigned short* A = (const unsigned short*)Av;
        ushort4 qa = *(const ushort4*)(A + (size_t)rowidx[ar]*lda + ka);
        a0 = bf2f(qa.x); a1 = bf2f(qa.y); a2 = bf2f(qa.z); a3 = bf2f(qa.w);
      } else {
        const float* A = (const float*)Av;
        float4 qa = *(const float4*)(A + (size_t)rowidx[ar]*lda + ka);
        a0 = qa.x; a1 = qa.y; a2 = qa.z; a3 = qa.w;
      }
    }
    float b0=0.f, b1=0.f, b2=0.f, b3=0.f;
    int kb = kk + bkr, nb = bn0 + bnv;
    if (kb < K && nb < N) {  // N % 4 == 0 -> whole quad in bounds
      float4 qb = *(const float4*)(B + (size_t)kb*N + nb);
      b0 = qb.x; b1 = qb.y; b2 = qb.z; b3 = qb.w;
    }
    As[akv+0][ar] = a0; As[akv+1][ar] = a1; As[akv+2][ar] = a2; As[akv+3][ar] = a3;
    Bs[bkr][bnv+0] = b0; Bs[bkr][bnv+1] = b1; Bs[bkr][bnv+2] = b2; Bs[bkr][bnv+3] = b3;
    __syncthreads();
    #pragma unroll
    for (int k = 0; k < BK; ++k) {
      v4f av = *(const v4f*)&As[k][ty << 2];
      v4f bv = *(const v4f*)&Bs[k][tx << 2];
      #pragma unroll
      for (int i = 0; i < 4; ++i)
        #pragma unroll
        for (int j = 0; j < 4; ++j)
          acc[i][j] += av[i] * bv[j];
    }
    __syncthreads();
  }
  #pragma unroll
  for (int i = 0; i < 4; ++i) {
    int m = bm0 + (ty << 2) + i;
    #pragma unroll
    for (int j = 0; j < 4; ++j) {
      int n = bn0 + (tx << 2) + j;
      if (n < N) C[(size_t)m*N + n] = f2bf(acc[i][j] + bias[n]);
    }
  }
}

// ---- sequential biLSTM: one block per direction ------------------------------
// Thread (g, q) = cell g (0..149), k-chunk q (0..4, 32 k each): holds U columns
// {g, g+150, g+300, g+450} for its k-range in VGPRs. h broadcast via LDS.
__global__ __launch_bounds__(768) void lstm_kernel(
    const unsigned short* __restrict__ pre_f, const unsigned short* __restrict__ pre_b,
    const float* __restrict__ Uf, const float* __restrict__ Ub,
    unsigned short* __restrict__ hidden /* [S][300] bf16 */)
{
  int dir = blockIdx.x;
  const unsigned short* pre = dir ? pre_b : pre_f;
  const float* U            = dir ? Ub : Uf;
  int tid = threadIdx.x;

  __shared__ __align__(16) float h_lds[160];     // 150 h + zero pad
  __shared__ __align__(16) float z2[3000];       // [q][gate*150 + g]
  __shared__ __align__(16) float pre_lds[2][600];

  bool fa = tid < 750;
  int g = tid % 150, q = tid / 150;
  int k0 = q << 5;                               // q*32

  v4f u[4][8];
  if (fa) {
    #pragma unroll
    for (int gt = 0; gt < 4; ++gt) {
      int col = g + gt*150;
      #pragma unroll
      for (int i = 0; i < 8; ++i)
        #pragma unroll
        for (int e = 0; e < 4; ++e) {
          int k = k0 + (i << 2) + e;
          u[gt][i][e] = (k < 150) ? U[(size_t)k*600 + col] : 0.f;
        }
    }
  }

  int t  = dir ? (S_LEN - 1) : 0;
  int dt = dir ? -1 : 1;
  if (tid < 160) h_lds[tid] = 0.f;
  if (tid < 600) pre_lds[0][tid] = bf2f(pre[(size_t)t*600 + tid]);
  float c = 0.f;
  __syncthreads();

  for (int s = 0; s < S_LEN; ++s) {
    float pn = 0.f;
    bool pf = (tid < 600) && (s + 1 < S_LEN);
    if (pf) pn = bf2f(pre[(size_t)(t + dt)*600 + tid]);   // prefetch next step

    if (fa) {
      v4f acc0 = {0.f,0.f,0.f,0.f}, acc1 = acc0, acc2 = acc0, acc3 = acc0;
      #pragma unroll
      for (int i = 0; i < 8; ++i) {
        v4f h4 = *(const v4f*)&h_lds[k0 + (i << 2)];   // broadcast read
        acc0 += h4 * u[0][i];
        acc1 += h4 * u[1][i];
        acc2 += h4 * u[2][i];
        acc3 += h4 * u[3][i];
      }
      int base = q*600 + g;
      z2[base      ] = (acc0[0]+acc0[1])+(acc0[2]+acc0[3]);
      z2[base + 150] = (acc1[0]+acc1[1])+(acc1[2]+acc1[3]);
      z2[base + 300] = (acc2[0]+acc2[1])+(acc2[2]+acc2[3]);
      z2[base + 450] = (acc3[0]+acc3[1])+(acc3[2]+acc3[3]);
    }
    if (pf) pre_lds[(s + 1) & 1][tid] = pn;
    __syncthreads();

    if (tid < 150) {
      const float* pc = pre_lds[s & 1];
      int i0 = tid, i1 = tid+150, i2 = tid+300, i3 = tid+450;
      float zi = pc[i0] + (((z2[i0]+z2[600+i0])+(z2[1200+i0]+z2[1800+i0]))+z2[2400+i0]);
      float zf = pc[i1] + (((z2[i1]+z2[600+i1])+(z2[1200+i1]+z2[1800+i1]))+z2[2400+i1]);
      float zg = pc[i2] + (((z2[i2]+z2[600+i2])+(z2[1200+i2]+z2[1800+i2]))+z2[2400+i2]);
      float zo = pc[i3] + (((z2[i3]+z2[600+i3])+(z2[1200+i3]+z2[1800+i3]))+z2[2400+i3]);
      float gi = 1.f/(1.f + __expf(-zi));
      float gf = 1.f/(1.f + __expf(-zf));
      float gg = tanhf(zg);
      float go = 1.f/(1.f + __expf(-zo));
      c = gf*c + gi*gg;
      float hv = go * tanhf(c);
      h_lds[tid] = hv;
      hidden[(size_t)t*300 + dir*150 + tid] = f2bf(hv);
    }
    __syncthreads();
    t += dt;
  }
}

// ---- per-word primary+secondary attention; atomic-reduce into HH -------------
__global__ __launch_bounds__(128) void attn_word(
    const unsigned short* __restrict__ outp,   // [S][300] bf16 (hidden @ W_p + b_p)
    const unsigned short* __restrict__ hid,    // [S][300] bf16
    const float* __restrict__ E,               // [V][300] f32
    const int* __restrict__ syn,               // [S][4]
    const float* __restrict__ W_s,             // [600]
    const float* __restrict__ b_s,             // [1]
    float* __restrict__ HH)                    // [600] accumulator
{
  int t = blockIdx.x, tid = threadIdx.x;
  __shared__ float s_out[300], s_hid[300], s_syn[4][300], s_m[300];
  __shared__ float s_red[8], s_sc[4], s_cf;

  int r0 = syn[t*4+0], r1 = syn[t*4+1], r2 = syn[t*4+2], r3 = syn[t*4+3];
  r0 = (r0 < 0) ? 0 : ((r0 >= VOCAB) ? VOCAB-1 : r0);
  r1 = (r1 < 0) ? 0 : ((r1 >= VOCAB) ? VOCAB-1 : r1);
  r2 = (r2 < 0) ? 0 : ((r2 >= VOCAB) ? VOCAB-1 : r2);
  r3 = (r3 < 0) ? 0 : ((r3 >= VOCAB) ? VOCAB-1 : r3);
  for (int d = tid; d < 300; d += 128) {
    s_out[d] = bf2f(outp[(size_t)t*300 + d]);
    s_hid[d] = bf2f(hid[(size_t)t*300 + d]);
    s_syn[0][d] = E[(size_t)r0*300 + d];
    s_syn[1][d] = E[(size_t)r1*300 + d];
    s_syn[2][d] = E[(size_t)r2*300 + d];
    s_syn[3][d] = E[(size_t)r3*300 + d];
  }
  __syncthreads();

  float p0=0.f, p1=0.f, p2=0.f, p3=0.f;
  for (int d = tid; d < 300; d += 128) {
    float o = s_out[d];
    p0 += o*s_syn[0][d]; p1 += o*s_syn[1][d];
    p2 += o*s_syn[2][d]; p3 += o*s_syn[3][d];
  }
  #pragma unroll
  for (int off = 32; off; off >>= 1) {
    p0 += __shfl_down(p0, off); p1 += __shfl_down(p1, off);
    p2 += __shfl_down(p2, off); p3 += __shfl_down(p3, off);
  }
  int wave = tid >> 6, lane = tid & 63;
  if (lane == 0) {
    s_red[wave*4+0] = p0; s_red[wave*4+1] = p1;
    s_red[wave*4+2] = p2; s_red[wave*4+3] = p3;
  }
  __syncthreads();
  // clamp keeps any upstream garbage finite (no-op for healthy values)
  if (tid < 4) s_sc[tid] = __expf(fminf(s_red[tid] + s_red[4 + tid], 50.f));
  __syncthreads();

  float sc0 = s_sc[0], sc1 = s_sc[1], sc2 = s_sc[2], sc3 = s_sc[3];
  float cp = 0.f;
  for (int d = tid; d < 300; d += 128) {
    float m = sc0*s_syn[0][d] + sc1*s_syn[1][d] + sc2*s_syn[2][d] + sc3*s_syn[3][d];
    s_m[d] = m;
    cp += s_hid[d]*W_s[d] + m*W_s[300 + d];
  }
  #pragma unroll
  for (int off = 32; off; off >>= 1) cp += __shfl_down(cp, off);
  if (lane == 0) s_red[wave] = cp;
  __syncthreads();
  if (tid == 0) s_cf = __expf(tanhf(s_red[0] + s_red[1] + b_s[0]));
  __syncthreads();

  float cf = s_cf;
  for (int d = tid; d < 300; d += 128) {
    atomicAdd(&HH[d],       cf * s_hid[d]);
    atomicAdd(&HH[300 + d], cf * s_m[d]);
  }
}

// ---- output heads ------------------------------------------------------------
__global__ void heads(const float* __restrict__ HH,
                      const float* __restrict__ W_emo, const float* __restrict__ b_emo,
                      const float* __restrict__ W_sent, const float* __restrict__ b_sent,
                      float* __restrict__ out) {
  int tid = threadIdx.x;
  if (tid < 8) {
    float a = 0.f;
    for (int d = 0; d < H2; ++d) a += HH[d] * W_emo[d*8 + tid];
    out[tid] = a + b_emo[tid];
  } else if (tid == 8) {
    float a = 0.f;
    for (int d = 0; d < H2; ++d) a += HH[d] * W_sent[d];
    out[8] = a + b_sent[0];
  }
}

extern "C" void kernel_launch(void* const* d_in, const int* in_sizes, int n_in,
                              void* d_out, int out_size, void* d_ws, size_t ws_size,
                              hipStream_t stream) {
  const int*   sentence = (const int*)d_in[0];
  const int*   syn_idx  = (const int*)d_in[1];
  const float* E        = (const float*)d_in[2];
  const float* W_f      = (const float*)d_in[3];
  const float* U_f      = (const float*)d_in[4];
  const float* b_f      = (const float*)d_in[5];
  const float* W_b      = (const float*)d_in[6];
  const float* U_b      = (const float*)d_in[7];
  const float* b_b      = (const float*)d_in[8];
  const float* W_p      = (const float*)d_in[9];
  const float* b_p      = (const float*)d_in[10];
  const float* W_s      = (const float*)d_in[11];
  const float* b_s      = (const float*)d_in[12];
  const float* W_emo    = (const float*)d_in[13];
  const float* b_emo    = (const float*)d_in[14];
  const float* W_sent   = (const float*)d_in[15];
  const float* b_sent   = (const float*)d_in[16];
  float*       outv     = (float*)d_out;

  // tight workspace, 16B-aligned offsets (bytes) — 14,748,160 total:
  //   HH      [600 f32]         @ 0
  //   hidden  [4096*300 bf16]   @ 2,560
  //   out_p   [4096*300 bf16]   @ 2,460,160
  //   pre_f   [4096*600 bf16]   @ 4,917,760
  //   pre_b   [4096*600 bf16]   @ 9,832,960
  unsigned char* ws = (unsigned char*)d_ws;
  float*          HH     = (float*)ws;
  unsigned short* hidden = (unsigned short*)(ws + 2560);
  unsigned short* out_p  = (unsigned short*)(ws + 2460160);
  unsigned short* pre_f  = (unsigned short*)(ws + 4917760);
  unsigned short* pre_b  = (unsigned short*)(ws + 9832960);

  if (ws_size < 14748160u) {   // deterministic guard: distinct bisect signal
    zero_out_f<<<1, 64, 0, stream>>>(outv, out_size);
    return;
  }

  zero_hh<<<1, 640, 0, stream>>>(HH);
  // pre[t] = emb[sentence[t]] @ W_dir + b_dir
  gemm_bias<false><<<dim3(10, 64), 256, 0, stream>>>(
      (const void*)E, sentence, D_EMB, VOCAB, W_f, b_f, pre_f, NG, D_EMB);
  gemm_bias<false><<<dim3(10, 64), 256, 0, stream>>>(
      (const void*)E, sentence, D_EMB, VOCAB, W_b, b_b, pre_b, NG, D_EMB);
  lstm_kernel<<<2, 768, 0, stream>>>(pre_f, pre_b, U_f, U_b, hidden);
  // out = hidden @ W_p + b_p
  gemm_bias<true><<<dim3(5, 64), 256, 0, stream>>>(
      (const void*)hidden, nullptr, HDIM, S_LEN, W_p, b_p, out_p, HDIM, HDIM);
  attn_word<<<S_LEN, 128, 0, stream>>>(out_p, hidden, E, syn_idx, W_s, b_s, HH);
  heads<<<1, 64, 0, stream>>>(HH, W_emo, b_emo, W_sent, b_sent, outv);
}

// Round 4
// 4096.897 us; speedup vs baseline: 1.3836x; 1.3836x over previous
//
#include <hip/hip_runtime.h>
#include <hip/hip_bf16.h>
#include <math.h>

#define S_LEN 4096
#define D_EMB 300
#define NG    600     // 4*HU
#define HDIM  300     // H
#define H2    600     // 2*H
#define VOCAB 100000

typedef float v4f __attribute__((ext_vector_type(4)));
typedef _Float16 f16x2 __attribute__((ext_vector_type(2)));
typedef _Float16 f16x8 __attribute__((ext_vector_type(8)));

__device__ __forceinline__ float bf2f(unsigned short u) {
  union { unsigned int i; float f; } v; v.i = ((unsigned int)u) << 16; return v.f;
}
__device__ __forceinline__ unsigned short f2bf(float f) {
  union { float f; unsigned int i; } v; v.f = f;
  return (unsigned short)((v.i + 0x7FFFu + ((v.i >> 16) & 1u)) >> 16);
}

// LDS-only barrier: does NOT drain vmcnt (global loads/stores stay in flight).
// LDS correctness: lgkmcnt(0) drains this wave's LDS ops; s_barrier orders waves.
__device__ __forceinline__ void bar_lds() {
  asm volatile("s_waitcnt lgkmcnt(0)\n\ts_barrier" ::: "memory");
}

__global__ void zero_hh(float* __restrict__ HH) {
  if (threadIdx.x < 640) HH[threadIdx.x] = 0.f;
}
__global__ void zero_out_f(float* __restrict__ o, int n) {
  if ((int)threadIdx.x < n) o[threadIdx.x] = 0.f;
}

// ---- GEMM: C[M,N](bf16) = gather(A)[M,K] @ B[K,N](f32) + bias(f32) -----------
#define BM 64
#define BN 64
#define BK 16
template<bool A_BF16>
__global__ __launch_bounds__(256) void gemm_bias(
    const void* __restrict__ Av,
    const int* __restrict__ idx, int lda, int nrowsA,
    const float* __restrict__ B,
    const float* __restrict__ bias,
    unsigned short* __restrict__ C,
    int N, int K)
{
  __shared__ __align__(16) float As[BK][BM + 4];
  __shared__ __align__(16) float Bs[BK][BN + 4];
  __shared__ int rowidx[BM];

  int tid = threadIdx.x;
  int bm0 = blockIdx.y * BM, bn0 = blockIdx.x * BN;
  if (tid < BM) {
    int r = idx ? idx[bm0 + tid] : (bm0 + tid);
    r = (r < 0) ? 0 : ((r >= nrowsA) ? (nrowsA - 1) : r);
    rowidx[tid] = r;
  }
  __syncthreads();

  int tx  = tid & 15, ty = tid >> 4;
  int ar  = tid >> 2, akv = (tid & 3) << 2;
  int bkr = tid >> 4, bnv = (tid & 15) << 2;

  float acc[4][4] = {};
  for (int kk = 0; kk < K; kk += BK) {
    float a0=0.f, a1=0.f, a2=0.f, a3=0.f;
    int ka = kk + akv;
    if (ka < K) {
      if (A_BF16) {
        const unsigned short* A = (const unsigned short*)Av;
        ushort4 qa = *(const ushort4*)(A + (size_t)rowidx[ar]*lda + ka);
        a0 = bf2f(qa.x); a1 = bf2f(qa.y); a2 = bf2f(qa.z); a3 = bf2f(qa.w);
      } else {
        const float* A = (const float*)Av;
        float4 qa = *(const float4*)(A + (size_t)rowidx[ar]*lda + ka);
        a0 = qa.x; a1 = qa.y; a2 = qa.z; a3 = qa.w;
      }
    }
    float b0=0.f, b1=0.f, b2=0.f, b3=0.f;
    int kb = kk + bkr, nb = bn0 + bnv;
    if (kb < K && nb < N) {
      float4 qb = *(const float4*)(B + (size_t)kb*N + nb);
      b0 = qb.x; b1 = qb.y; b2 = qb.z; b3 = qb.w;
    }
    As[akv+0][ar] = a0; As[akv+1][ar] = a1; As[akv+2][ar] = a2; As[akv+3][ar] = a3;
    Bs[bkr][bnv+0] = b0; Bs[bkr][bnv+1] = b1; Bs[bkr][bnv+2] = b2; Bs[bkr][bnv+3] = b3;
    __syncthreads();
    #pragma unroll
    for (int k = 0; k < BK; ++k) {
      v4f av = *(const v4f*)&As[k][ty << 2];
      v4f bv = *(const v4f*)&Bs[k][tx << 2];
      #pragma unroll
      for (int i = 0; i < 4; ++i)
        #pragma unroll
        for (int j = 0; j < 4; ++j)
          acc[i][j] += av[i] * bv[j];
    }
    __syncthreads();
  }
  #pragma unroll
  for (int i = 0; i < 4; ++i) {
    int m = bm0 + (ty << 2) + i;
    #pragma unroll
    for (int j = 0; j < 4; ++j) {
      int n = bn0 + (tx << 2) + j;
      if (n < N) C[(size_t)m*N + n] = f2bf(acc[i][j] + bias[n]);
    }
  }
}

// ---- sequential biLSTM: one block per direction, v_dot2 f16 matvec -----------
// Phase A (750 thr): thread (c4,q) owns 4 consecutive cols j0=4*c4, k-chunk
//   q*32..+31 (k>=150 zero-padded); U in VGPRs as f16 pairs; h broadcast from
//   LDS (f16); one ds_write_b128 of 4 partials.
// Phase B (600 thr): per-column z reduction + fast sigmoid/tanh -> act[600].
// Phase C (150 thr): c = f*c + i*g; h = o*tanh(c); h -> LDS (f16) + 8-step
//   bf16 history ring, flushed as coalesced dword stores every 8 steps.
__global__ __launch_bounds__(768) void lstm_kernel(
    const unsigned short* __restrict__ pre_f, const unsigned short* __restrict__ pre_b,
    const float* __restrict__ Uf, const float* __restrict__ Ub,
    unsigned short* __restrict__ hidden /* [S][300] bf16 */)
{
  const int dir = blockIdx.x;
  const unsigned short* pre = dir ? pre_b : pre_f;
  const float* U            = dir ? Ub : Uf;
  const int tid = threadIdx.x;

  __shared__ __align__(16) unsigned short h_u16[160];      // h as f16 (pad=0)
  __shared__ __align__(16) float z2[3000];                 // [q][600]
  __shared__ __align__(16) float act[600];
  __shared__ __align__(16) float ring[3][600];             // pre (f32) ring
  __shared__ __align__(16) unsigned short h_hist[8][160];  // bf16 h history

  const bool faP = tid < 750;
  const int c4 = tid % 150, q = tid / 150;
  const int j0 = c4 << 2;          // 4 consecutive columns
  const int k0 = q << 5;           // 32 k per chunk (k=150..159 padded)

  // preload U fragment: 4 cols x 16 f16-pairs = 64 VGPRs
  f16x2 u[4][16];
  if (faP) {
    #pragma unroll
    for (int cc = 0; cc < 4; ++cc)
      #pragma unroll
      for (int p = 0; p < 16; ++p) {
        int k = k0 + (p << 1);
        float a = (k     < 150) ? U[(size_t)k    *600 + j0 + cc] : 0.f;
        float b = (k + 1 < 150) ? U[(size_t)(k+1)*600 + j0 + cc] : 0.f;
        f16x2 v; v[0] = (_Float16)a; v[1] = (_Float16)b;
        u[cc][p] = v;
      }
  }

  int t  = dir ? (S_LEN - 1) : 0;
  const int dt = dir ? -1 : 1;

  if (tid < 160) h_u16[tid] = 0;                 // h=0 (f16), incl. pad
  unsigned short nxt1 = 0;
  if (tid < 600) {
    ring[0][tid] = bf2f(pre[(size_t)t*600 + tid]);
    nxt1 = pre[(size_t)(t + dt)*600 + tid];      // for step 1
  }
  float c = 0.f;
  __syncthreads();

  const _Float16* hf = (const _Float16*)h_u16;

  for (int s = 0; s < S_LEN; ++s) {
    // ---- flush 8-step h history (off the critical path; raw barriers never
    //      drain these stores) ----
    if ((s & 7) == 0 && s) {
      if (tid < 600) {
        int sub = tid / 75, w = (tid % 75) << 1;
        int sp  = s - 8 + sub;
        int tp  = dir ? (S_LEN - 1 - sp) : sp;
        unsigned int v = *(const unsigned int*)&h_hist[sub][w];
        *(unsigned int*)(hidden + (size_t)tp*300 + dir*150 + w) = v;
      }
    }
    // ---- issue global prefetch for step s+2 (consumed next step) ----
    unsigned short nxt2 = 0;
    if (tid < 600 && s + 2 < S_LEN) nxt2 = pre[(size_t)(t + 2*dt)*600 + tid];

    // ---- Phase A: matvec partials via v_dot2_f32_f16 ----
    if (faP) {
      f16x2 hp[16];
      *(f16x8*)&hp[0]  = *(const f16x8*)&hf[k0];
      *(f16x8*)&hp[4]  = *(const f16x8*)&hf[k0 + 8];
      *(f16x8*)&hp[8]  = *(const f16x8*)&hf[k0 + 16];
      *(f16x8*)&hp[12] = *(const f16x8*)&hf[k0 + 24];
      float a0 = 0.f, a1 = 0.f, a2 = 0.f, a3 = 0.f;
      #pragma unroll
      for (int p = 0; p < 16; ++p) {
        a0 = __builtin_amdgcn_fdot2(hp[p], u[0][p], a0, false);
        a1 = __builtin_amdgcn_fdot2(hp[p], u[1][p], a1, false);
        a2 = __builtin_amdgcn_fdot2(hp[p], u[2][p], a2, false);
        a3 = __builtin_amdgcn_fdot2(hp[p], u[3][p], a3, false);
      }
      v4f zp; zp[0] = a0; zp[1] = a1; zp[2] = a2; zp[3] = a3;
      *(v4f*)&z2[q*600 + j0] = zp;               // one ds_write_b128
    }
    // stage prefetched pre (loaded last step) into the ring
    if (tid < 600) ring[(s + 1) % 3][tid] = bf2f(nxt1);
    nxt1 = nxt2;
    bar_lds();

    // ---- Phase B: per-column reduce + nonlinearity (600 lanes) ----
    if (tid < 600) {
      int j = tid;
      float z = ring[s % 3][j]
              + ((z2[j] + z2[600 + j]) + (z2[1200 + j] + z2[1800 + j]))
              + z2[2400 + j];
      bool is_g = (j >= 300) & (j < 450);
      float e = __expf(is_g ? (2.f * z) : (-z));
      float r = __builtin_amdgcn_rcpf(1.f + e);
      act[j] = is_g ? (1.f - 2.f * r) : r;       // tanh : sigmoid
    }
    bar_lds();

    // ---- Phase C: cell update (150 lanes) ----
    if (tid < 150) {
      float gi = act[tid], gf = act[150 + tid], gg = act[300 + tid], go = act[450 + tid];
      c = gf * c + gi * gg;
      float e = __expf(2.f * c);
      float th = 1.f - 2.f * __builtin_amdgcn_rcpf(e + 1.f);
      float hv = go * th;
      ((_Float16*)h_u16)[tid] = (_Float16)hv;
      h_hist[s & 7][tid] = f2bf(hv);
    }
    bar_lds();
    t += dt;
  }

  // final flush (steps 4088..4095); stores drain at kernel end
  if (tid < 600) {
    int sub = tid / 75, w = (tid % 75) << 1;
    int sp  = S_LEN - 8 + sub;
    int tp  = dir ? (S_LEN - 1 - sp) : sp;
    unsigned int v = *(const unsigned int*)&h_hist[sub][w];
    *(unsigned int*)(hidden + (size_t)tp*300 + dir*150 + w) = v;
  }
}

// ---- per-word primary+secondary attention; atomic-reduce into HH -------------
__global__ __launch_bounds__(128) void attn_word(
    const unsigned short* __restrict__ outp,   // [S][300] bf16
    const unsigned short* __restrict__ hid,    // [S][300] bf16
    const float* __restrict__ E,               // [V][300] f32
    const int* __restrict__ syn,               // [S][4]
    const float* __restrict__ W_s,             // [600]
    const float* __restrict__ b_s,             // [1]
    float* __restrict__ HH)                    // [600] accumulator
{
  int t = blockIdx.x, tid = threadIdx.x;
  __shared__ float s_out[300], s_hid[300], s_syn[4][300], s_m[300];
  __shared__ float s_red[8], s_sc[4], s_cf;

  int r0 = syn[t*4+0], r1 = syn[t*4+1], r2 = syn[t*4+2], r3 = syn[t*4+3];
  r0 = (r0 < 0) ? 0 : ((r0 >= VOCAB) ? VOCAB-1 : r0);
  r1 = (r1 < 0) ? 0 : ((r1 >= VOCAB) ? VOCAB-1 : r1);
  r2 = (r2 < 0) ? 0 : ((r2 >= VOCAB) ? VOCAB-1 : r2);
  r3 = (r3 < 0) ? 0 : ((r3 >= VOCAB) ? VOCAB-1 : r3);
  for (int d = tid; d < 300; d += 128) {
    s_out[d] = bf2f(outp[(size_t)t*300 + d]);
    s_hid[d] = bf2f(hid[(size_t)t*300 + d]);
    s_syn[0][d] = E[(size_t)r0*300 + d];
    s_syn[1][d] = E[(size_t)r1*300 + d];
    s_syn[2][d] = E[(size_t)r2*300 + d];
    s_syn[3][d] = E[(size_t)r3*300 + d];
  }
  __syncthreads();

  float p0=0.f, p1=0.f, p2=0.f, p3=0.f;
  for (int d = tid; d < 300; d += 128) {
    float o = s_out[d];
    p0 += o*s_syn[0][d]; p1 += o*s_syn[1][d];
    p2 += o*s_syn[2][d]; p3 += o*s_syn[3][d];
  }
  #pragma unroll
  for (int off = 32; off; off >>= 1) {
    p0 += __shfl_down(p0, off); p1 += __shfl_down(p1, off);
    p2 += __shfl_down(p2, off); p3 += __shfl_down(p3, off);
  }
  int wave = tid >> 6, lane = tid & 63;
  if (lane == 0) {
    s_red[wave*4+0] = p0; s_red[wave*4+1] = p1;
    s_red[wave*4+2] = p2; s_red[wave*4+3] = p3;
  }
  __syncthreads();
  if (tid < 4) s_sc[tid] = __expf(fminf(s_red[tid] + s_red[4 + tid], 50.f));
  __syncthreads();

  float sc0 = s_sc[0], sc1 = s_sc[1], sc2 = s_sc[2], sc3 = s_sc[3];
  float cp = 0.f;
  for (int d = tid; d < 300; d += 128) {
    float m = sc0*s_syn[0][d] + sc1*s_syn[1][d] + sc2*s_syn[2][d] + sc3*s_syn[3][d];
    s_m[d] = m;
    cp += s_hid[d]*W_s[d] + m*W_s[300 + d];
  }
  #pragma unroll
  for (int off = 32; off; off >>= 1) cp += __shfl_down(cp, off);
  if (lane == 0) s_red[wave] = cp;
  __syncthreads();
  if (tid == 0) s_cf = __expf(tanhf(s_red[0] + s_red[1] + b_s[0]));
  __syncthreads();

  float cf = s_cf;
  for (int d = tid; d < 300; d += 128) {
    atomicAdd(&HH[d],       cf * s_hid[d]);
    atomicAdd(&HH[300 + d], cf * s_m[d]);
  }
}

// ---- output heads ------------------------------------------------------------
__global__ void heads(const float* __restrict__ HH,
                      const float* __restrict__ W_emo, const float* __restrict__ b_emo,
                      const float* __restrict__ W_sent, const float* __restrict__ b_sent,
                      float* __restrict__ out) {
  int tid = threadIdx.x;
  if (tid < 8) {
    float a = 0.f;
    for (int d = 0; d < H2; ++d) a += HH[d] * W_emo[d*8 + tid];
    out[tid] = a + b_emo[tid];
  } else if (tid == 8) {
    float a = 0.f;
    for (int d = 0; d < H2; ++d) a += HH[d] * W_sent[d];
    out[8] = a + b_sent[0];
  }
}

extern "C" void kernel_launch(void* const* d_in, const int* in_sizes, int n_in,
                              void* d_out, int out_size, void* d_ws, size_t ws_size,
                              hipStream_t stream) {
  const int*   sentence = (const int*)d_in[0];
  const int*   syn_idx  = (const int*)d_in[1];
  const float* E        = (const float*)d_in[2];
  const float* W_f      = (const float*)d_in[3];
  const float* U_f      = (const float*)d_in[4];
  const float* b_f      = (const float*)d_in[5];
  const float* W_b      = (const float*)d_in[6];
  const float* U_b      = (const float*)d_in[7];
  const float* b_b      = (const float*)d_in[8];
  const float* W_p      = (const float*)d_in[9];
  const float* b_p      = (const float*)d_in[10];
  const float* W_s      = (const float*)d_in[11];
  const float* b_s      = (const float*)d_in[12];
  const float* W_emo    = (const float*)d_in[13];
  const float* b_emo    = (const float*)d_in[14];
  const float* W_sent   = (const float*)d_in[15];
  const float* b_sent   = (const float*)d_in[16];
  float*       outv     = (float*)d_out;

  // workspace layout (16B-aligned, 14,748,160 B total)
  unsigned char* ws = (unsigned char*)d_ws;
  float*          HH     = (float*)ws;
  unsigned short* hidden = (unsigned short*)(ws + 2560);
  unsigned short* out_p  = (unsigned short*)(ws + 2460160);
  unsigned short* pre_f  = (unsigned short*)(ws + 4917760);
  unsigned short* pre_b  = (unsigned short*)(ws + 9832960);

  if (ws_size < 14748160u) {
    zero_out_f<<<1, 64, 0, stream>>>(outv, out_size);
    return;
  }

  zero_hh<<<1, 640, 0, stream>>>(HH);
  gemm_bias<false><<<dim3(10, 64), 256, 0, stream>>>(
      (const void*)E, sentence, D_EMB, VOCAB, W_f, b_f, pre_f, NG, D_EMB);
  gemm_bias<false><<<dim3(10, 64), 256, 0, stream>>>(
      (const void*)E, sentence, D_EMB, VOCAB, W_b, b_b, pre_b, NG, D_EMB);
  lstm_kernel<<<2, 768, 0, stream>>>(pre_f, pre_b, U_f, U_b, hidden);
  gemm_bias<true><<<dim3(5, 64), 256, 0, stream>>>(
      (const void*)hidden, nullptr, HDIM, S_LEN, W_p, b_p, out_p, HDIM, HDIM);
  attn_word<<<S_LEN, 128, 0, stream>>>(out_p, hidden, E, syn_idx, W_s, b_s, HH);
  heads<<<1, 64, 0, stream>>>(HH, W_emo, b_emo, W_sent, b_sent, outv);
}

// Round 5
// 3620.751 us; speedup vs baseline: 1.5656x; 1.1315x over previous
//
#include <hip/hip_runtime.h>
#include <hip/hip_bf16.h>
#include <math.h>

#define S_LEN 4096
#define D_EMB 300
#define NG    600     // 4*HU
#define HDIM  300     // H
#define H2    600     // 2*H
#define VOCAB 100000

typedef float v4f __attribute__((ext_vector_type(4)));
typedef _Float16 f16x2 __attribute__((ext_vector_type(2)));
typedef _Float16 f16x8 __attribute__((ext_vector_type(8)));

__device__ __forceinline__ float bf2f(unsigned short u) {
  union { unsigned int i; float f; } v; v.i = ((unsigned int)u) << 16; return v.f;
}
__device__ __forceinline__ unsigned short f2bf(float f) {
  union { float f; unsigned int i; } v; v.f = f;
  return (unsigned short)((v.i + 0x7FFFu + ((v.i >> 16) & 1u)) >> 16);
}

// LDS-only barrier: drains lgkmcnt (LDS) but NOT vmcnt -> global loads/stores
// stay in flight across the barrier.
__device__ __forceinline__ void bar_lds() {
  asm volatile("s_waitcnt lgkmcnt(0)\n\ts_barrier" ::: "memory");
}

__global__ void zero_hh(float* __restrict__ HH) {
  if (threadIdx.x < 640) HH[threadIdx.x] = 0.f;
}
__global__ void zero_out_f(float* __restrict__ o, int n) {
  if ((int)threadIdx.x < n) o[threadIdx.x] = 0.f;
}

// ---- GEMM: C[M,N](bf16) = gather(A)[M,K] @ B[K,N](f32) + bias(f32) -----------
#define BM 64
#define BN 64
#define BK 16
template<bool A_BF16>
__global__ __launch_bounds__(256) void gemm_bias(
    const void* __restrict__ Av,
    const int* __restrict__ idx, int lda, int nrowsA,
    const float* __restrict__ B,
    const float* __restrict__ bias,
    unsigned short* __restrict__ C,
    int N, int K)
{
  __shared__ __align__(16) float As[BK][BM + 4];
  __shared__ __align__(16) float Bs[BK][BN + 4];
  __shared__ int rowidx[BM];

  int tid = threadIdx.x;
  int bm0 = blockIdx.y * BM, bn0 = blockIdx.x * BN;
  if (tid < BM) {
    int r = idx ? idx[bm0 + tid] : (bm0 + tid);
    r = (r < 0) ? 0 : ((r >= nrowsA) ? (nrowsA - 1) : r);
    rowidx[tid] = r;
  }
  __syncthreads();

  int tx  = tid & 15, ty = tid >> 4;
  int ar  = tid >> 2, akv = (tid & 3) << 2;
  int bkr = tid >> 4, bnv = (tid & 15) << 2;

  float acc[4][4] = {};
  for (int kk = 0; kk < K; kk += BK) {
    float a0=0.f, a1=0.f, a2=0.f, a3=0.f;
    int ka = kk + akv;
    if (ka < K) {
      if (A_BF16) {
        const unsigned short* A = (const unsigned short*)Av;
        ushort4 qa = *(const ushort4*)(A + (size_t)rowidx[ar]*lda + ka);
        a0 = bf2f(qa.x); a1 = bf2f(qa.y); a2 = bf2f(qa.z); a3 = bf2f(qa.w);
      } else {
        const float* A = (const float*)Av;
        float4 qa = *(const float4*)(A + (size_t)rowidx[ar]*lda + ka);
        a0 = qa.x; a1 = qa.y; a2 = qa.z; a3 = qa.w;
      }
    }
    float b0=0.f, b1=0.f, b2=0.f, b3=0.f;
    int kb = kk + bkr, nb = bn0 + bnv;
    if (kb < K && nb < N) {
      float4 qb = *(const float4*)(B + (size_t)kb*N + nb);
      b0 = qb.x; b1 = qb.y; b2 = qb.z; b3 = qb.w;
    }
    As[akv+0][ar] = a0; As[akv+1][ar] = a1; As[akv+2][ar] = a2; As[akv+3][ar] = a3;
    Bs[bkr][bnv+0] = b0; Bs[bkr][bnv+1] = b1; Bs[bkr][bnv+2] = b2; Bs[bkr][bnv+3] = b3;
    __syncthreads();
    #pragma unroll
    for (int k = 0; k < BK; ++k) {
      v4f av = *(const v4f*)&As[k][ty << 2];
      v4f bv = *(const v4f*)&Bs[k][tx << 2];
      #pragma unroll
      for (int i = 0; i < 4; ++i)
        #pragma unroll
        for (int j = 0; j < 4; ++j)
          acc[i][j] += av[i] * bv[j];
    }
    __syncthreads();
  }
  #pragma unroll
  for (int i = 0; i < 4; ++i) {
    int m = bm0 + (ty << 2) + i;
    #pragma unroll
    for (int j = 0; j < 4; ++j) {
      int n = bn0 + (tx << 2) + j;
      if (n < N) C[(size_t)m*N + n] = f2bf(acc[i][j] + bias[n]);
    }
  }
}

// ---- sequential biLSTM: one block per direction, v_dot2 f16 matvec -----------
// Per step (2 barriers):
//   Phase A (750 thr): thread (c4,q) = 4 consecutive cols j0=4*c4, k-chunk
//     q*32..+31; U in VGPRs as f16 pairs; h broadcast from LDS (f16);
//     one ds_write_b128 of 4 partials. NOTHING else in these waves.
//   Phase BC (150 thr, lane=cell): reads its 20 z2 partials + pre (registers,
//     prefetched from global 2 steps ahead), 4 gate activations, cell update,
//     h -> LDS f16 + bf16 history ring (flushed every 8 steps, coalesced).
__global__ __launch_bounds__(768) void lstm_kernel(
    const unsigned short* __restrict__ pre_f, const unsigned short* __restrict__ pre_b,
    const float* __restrict__ Uf, const float* __restrict__ Ub,
    unsigned short* __restrict__ hidden /* [S][300] bf16 */)
{
  const int dir = blockIdx.x;
  const unsigned short* pre = dir ? pre_b : pre_f;
  const float* U            = dir ? Ub : Uf;
  const int tid = threadIdx.x;

  __shared__ __align__(16) unsigned short h_u16[160];      // h as f16 (pad=0)
  __shared__ __align__(16) float z2[3000];                 // [q][600]
  __shared__ __align__(16) unsigned short h_hist[8][160];  // bf16 h history

  const bool faP = tid < 750;
  const bool bc  = tid < 150;
  const int c4 = tid % 150, q = tid / 150;
  const int j0 = c4 << 2;          // 4 consecutive columns
  const int k0 = q << 5;           // 32 k per chunk (k=150..159 padded)

  // preload U fragment: 4 cols x 16 f16-pairs = 64 VGPRs
  f16x2 u[4][16];
  if (faP) {
    #pragma unroll
    for (int cc = 0; cc < 4; ++cc)
      #pragma unroll
      for (int p = 0; p < 16; ++p) {
        int k = k0 + (p << 1);
        float a = (k     < 150) ? U[(size_t)k    *600 + j0 + cc] : 0.f;
        float b = (k + 1 < 150) ? U[(size_t)(k+1)*600 + j0 + cc] : 0.f;
        f16x2 v; v[0] = (_Float16)a; v[1] = (_Float16)b;
        u[cc][p] = v;
      }
  }

  const int t0 = dir ? (S_LEN - 1) : 0;
  const int dt = dir ? -1 : 1;
  const ptrdiff_t pstep = (ptrdiff_t)dt * 600;

  if (tid < 160) h_u16[tid] = 0;                 // h=0 (f16), incl. pad

  // BC-lane pre values in registers: pA = step s, pB = s+1, loaded ahead.
  float pA0=0,pA1=0,pA2=0,pA3=0, pB0=0,pB1=0,pB2=0,pB3=0;
  const unsigned short* pre2 = pre + (ptrdiff_t)t0*600 + 2*pstep;  // s+2 base
  if (bc) {
    const unsigned short* g0 = pre + (ptrdiff_t)t0*600;
    pA0 = bf2f(g0[tid]); pA1 = bf2f(g0[tid+150]);
    pA2 = bf2f(g0[tid+300]); pA3 = bf2f(g0[tid+450]);
    const unsigned short* g1 = g0 + pstep;
    pB0 = bf2f(g1[tid]); pB1 = bf2f(g1[tid+150]);
    pB2 = bf2f(g1[tid+300]); pB3 = bf2f(g1[tid+450]);
  }
  float c = 0.f;
  __syncthreads();

  const _Float16* hf = (const _Float16*)h_u16;

  for (int s8 = 0; s8 < S_LEN/8; ++s8) {
    // flush previous 8 steps' h (raw barriers never drain these stores)
    if (s8 && tid < 600) {
      int sub = tid / 75, w = (tid % 75) << 1;
      int sp  = (s8 << 3) - 8 + sub;
      int tp  = dir ? (S_LEN - 1 - sp) : sp;
      *(unsigned int*)(hidden + (size_t)tp*300 + dir*150 + w) =
          *(const unsigned int*)&h_hist[sub][w];
    }
    #pragma unroll
    for (int ss = 0; ss < 8; ++ss) {
      const int s = (s8 << 3) + ss;
      // ---- Phase A: matvec partials via v_dot2_f32_f16 ----
      if (faP) {
        f16x2 hp[16];
        *(f16x8*)&hp[0]  = *(const f16x8*)&hf[k0];
        *(f16x8*)&hp[4]  = *(const f16x8*)&hf[k0 + 8];
        *(f16x8*)&hp[8]  = *(const f16x8*)&hf[k0 + 16];
        *(f16x8*)&hp[12] = *(const f16x8*)&hf[k0 + 24];
        float a0 = 0.f, a1 = 0.f, a2 = 0.f, a3 = 0.f;
        #pragma unroll
        for (int p = 0; p < 16; ++p) {
          a0 = __builtin_amdgcn_fdot2(hp[p], u[0][p], a0, false);
          a1 = __builtin_amdgcn_fdot2(hp[p], u[1][p], a1, false);
          a2 = __builtin_amdgcn_fdot2(hp[p], u[2][p], a2, false);
          a3 = __builtin_amdgcn_fdot2(hp[p], u[3][p], a3, false);
        }
        v4f zp; zp[0] = a0; zp[1] = a1; zp[2] = a2; zp[3] = a3;
        *(v4f*)&z2[q*600 + j0] = zp;             // one ds_write_b128
      }
      // ---- BC prefetch for step s+2 (registers; overlaps 2 full steps) ----
      float pC0=0,pC1=0,pC2=0,pC3=0;
      if (bc && s + 2 < S_LEN) {
        pC0 = bf2f(pre2[tid]);       pC1 = bf2f(pre2[tid+150]);
        pC2 = bf2f(pre2[tid+300]);   pC3 = bf2f(pre2[tid+450]);
      }
      bar_lds();

      // ---- Phase BC: gate reduce + activations + cell update (150 lanes) ----
      if (bc) {
        float zi = pA0 + ((z2[tid      ] + z2[600+tid      ]) + (z2[1200+tid      ] + z2[1800+tid      ])) + z2[2400+tid      ];
        float zf = pA1 + ((z2[tid + 150] + z2[600+tid + 150]) + (z2[1200+tid + 150] + z2[1800+tid + 150])) + z2[2400+tid + 150];
        float zg = pA2 + ((z2[tid + 300] + z2[600+tid + 300]) + (z2[1200+tid + 300] + z2[1800+tid + 300])) + z2[2400+tid + 300];
        float zo = pA3 + ((z2[tid + 450] + z2[600+tid + 450]) + (z2[1200+tid + 450] + z2[1800+tid + 450])) + z2[2400+tid + 450];
        float gi = __builtin_amdgcn_rcpf(1.f + __expf(-zi));
        float gf = __builtin_amdgcn_rcpf(1.f + __expf(-zf));
        float gg = 1.f - 2.f * __builtin_amdgcn_rcpf(__expf(2.f * zg) + 1.f);
        float go = __builtin_amdgcn_rcpf(1.f + __expf(-zo));
        c = gf * c + gi * gg;
        float th = 1.f - 2.f * __builtin_amdgcn_rcpf(__expf(2.f * c) + 1.f);
        float hv = go * th;
        ((_Float16*)h_u16)[tid] = (_Float16)hv;
        h_hist[ss][tid] = f2bf(hv);
        pA0 = pB0; pA1 = pB1; pA2 = pB2; pA3 = pB3;
        pB0 = pC0; pB1 = pC1; pB2 = pC2; pB3 = pC3;
      }
      bar_lds();
      pre2 += pstep;
    }
  }

  // final flush (steps 4088..4095); stores drain at kernel end
  if (tid < 600) {
    int sub = tid / 75, w = (tid % 75) << 1;
    int sp  = S_LEN - 8 + sub;
    int tp  = dir ? (S_LEN - 1 - sp) : sp;
    *(unsigned int*)(hidden + (size_t)tp*300 + dir*150 + w) =
        *(const unsigned int*)&h_hist[sub][w];
  }
}

// ---- per-word primary+secondary attention; atomic-reduce into HH -------------
__global__ __launch_bounds__(128) void attn_word(
    const unsigned short* __restrict__ outp,   // [S][300] bf16
    const unsigned short* __restrict__ hid,    // [S][300] bf16
    const float* __restrict__ E,               // [V][300] f32
    const int* __restrict__ syn,               // [S][4]
    const float* __restrict__ W_s,             // [600]
    const float* __restrict__ b_s,             // [1]
    float* __restrict__ HH)                    // [600] accumulator
{
  int t = blockIdx.x, tid = threadIdx.x;
  __shared__ float s_out[300], s_hid[300], s_syn[4][300], s_m[300];
  __shared__ float s_red[8], s_sc[4], s_cf;

  int r0 = syn[t*4+0], r1 = syn[t*4+1], r2 = syn[t*4+2], r3 = syn[t*4+3];
  r0 = (r0 < 0) ? 0 : ((r0 >= VOCAB) ? VOCAB-1 : r0);
  r1 = (r1 < 0) ? 0 : ((r1 >= VOCAB) ? VOCAB-1 : r1);
  r2 = (r2 < 0) ? 0 : ((r2 >= VOCAB) ? VOCAB-1 : r2);
  r3 = (r3 < 0) ? 0 : ((r3 >= VOCAB) ? VOCAB-1 : r3);
  for (int d = tid; d < 300; d += 128) {
    s_out[d] = bf2f(outp[(size_t)t*300 + d]);
    s_hid[d] = bf2f(hid[(size_t)t*300 + d]);
    s_syn[0][d] = E[(size_t)r0*300 + d];
    s_syn[1][d] = E[(size_t)r1*300 + d];
    s_syn[2][d] = E[(size_t)r2*300 + d];
    s_syn[3][d] = E[(size_t)r3*300 + d];
  }
  __syncthreads();

  float p0=0.f, p1=0.f, p2=0.f, p3=0.f;
  for (int d = tid; d < 300; d += 128) {
    float o = s_out[d];
    p0 += o*s_syn[0][d]; p1 += o*s_syn[1][d];
    p2 += o*s_syn[2][d]; p3 += o*s_syn[3][d];
  }
  #pragma unroll
  for (int off = 32; off; off >>= 1) {
    p0 += __shfl_down(p0, off); p1 += __shfl_down(p1, off);
    p2 += __shfl_down(p2, off); p3 += __shfl_down(p3, off);
  }
  int wave = tid >> 6, lane = tid & 63;
  if (lane == 0) {
    s_red[wave*4+0] = p0; s_red[wave*4+1] = p1;
    s_red[wave*4+2] = p2; s_red[wave*4+3] = p3;
  }
  __syncthreads();
  if (tid < 4) s_sc[tid] = __expf(fminf(s_red[tid] + s_red[4 + tid], 50.f));
  __syncthreads();

  float sc0 = s_sc[0], sc1 = s_sc[1], sc2 = s_sc[2], sc3 = s_sc[3];
  float cp = 0.f;
  for (int d = tid; d < 300; d += 128) {
    float m = sc0*s_syn[0][d] + sc1*s_syn[1][d] + sc2*s_syn[2][d] + sc3*s_syn[3][d];
    s_m[d] = m;
    cp += s_hid[d]*W_s[d] + m*W_s[300 + d];
  }
  #pragma unroll
  for (int off = 32; off; off >>= 1) cp += __shfl_down(cp, off);
  if (lane == 0) s_red[wave] = cp;
  __syncthreads();
  if (tid == 0) s_cf = __expf(tanhf(s_red[0] + s_red[1] + b_s[0]));
  __syncthreads();

  float cf = s_cf;
  for (int d = tid; d < 300; d += 128) {
    atomicAdd(&HH[d],       cf * s_hid[d]);
    atomicAdd(&HH[300 + d], cf * s_m[d]);
  }
}

// ---- output heads ------------------------------------------------------------
__global__ void heads(const float* __restrict__ HH,
                      const float* __restrict__ W_emo, const float* __restrict__ b_emo,
                      const float* __restrict__ W_sent, const float* __restrict__ b_sent,
                      float* __restrict__ out) {
  int tid = threadIdx.x;
  if (tid < 8) {
    float a = 0.f;
    for (int d = 0; d < H2; ++d) a += HH[d] * W_emo[d*8 + tid];
    out[tid] = a + b_emo[tid];
  } else if (tid == 8) {
    float a = 0.f;
    for (int d = 0; d < H2; ++d) a += HH[d] * W_sent[d];
    out[8] = a + b_sent[0];
  }
}

extern "C" void kernel_launch(void* const* d_in, const int* in_sizes, int n_in,
                              void* d_out, int out_size, void* d_ws, size_t ws_size,
                              hipStream_t stream) {
  const int*   sentence = (const int*)d_in[0];
  const int*   syn_idx  = (const int*)d_in[1];
  const float* E        = (const float*)d_in[2];
  const float* W_f      = (const float*)d_in[3];
  const float* U_f      = (const float*)d_in[4];
  const float* b_f      = (const float*)d_in[5];
  const float* W_b      = (const float*)d_in[6];
  const float* U_b      = (const float*)d_in[7];
  const float* b_b      = (const float*)d_in[8];
  const float* W_p      = (const float*)d_in[9];
  const float* b_p      = (const float*)d_in[10];
  const float* W_s      = (const float*)d_in[11];
  const float* b_s      = (const float*)d_in[12];
  const float* W_emo    = (const float*)d_in[13];
  const float* b_emo    = (const float*)d_in[14];
  const float* W_sent   = (const float*)d_in[15];
  const float* b_sent   = (const float*)d_in[16];
  float*       outv     = (float*)d_out;

  // workspace layout (16B-aligned, 14,748,160 B total)
  unsigned char* ws = (unsigned char*)d_ws;
  float*          HH     = (float*)ws;
  unsigned short* hidden = (unsigned short*)(ws + 2560);
  unsigned short* out_p  = (unsigned short*)(ws + 2460160);
  unsigned short* pre_f  = (unsigned short*)(ws + 4917760);
  unsigned short* pre_b  = (unsigned short*)(ws + 9832960);

  if (ws_size < 14748160u) {
    zero_out_f<<<1, 64, 0, stream>>>(outv, out_size);
    return;
  }

  zero_hh<<<1, 640, 0, stream>>>(HH);
  gemm_bias<false><<<dim3(10, 64), 256, 0, stream>>>(
      (const void*)E, sentence, D_EMB, VOCAB, W_f, b_f, pre_f, NG, D_EMB);
  gemm_bias<false><<<dim3(10, 64), 256, 0, stream>>>(
      (const void*)E, sentence, D_EMB, VOCAB, W_b, b_b, pre_b, NG, D_EMB);
  lstm_kernel<<<2, 768, 0, stream>>>(pre_f, pre_b, U_f, U_b, hidden);
  gemm_bias<true><<<dim3(5, 64), 256, 0, stream>>>(
      (const void*)hidden, nullptr, HDIM, S_LEN, W_p, b_p, out_p, HDIM, HDIM);
  attn_word<<<S_LEN, 128, 0, stream>>>(out_p, hidden, E, syn_idx, W_s, b_s, HH);
  heads<<<1, 64, 0, stream>>>(HH, W_emo, b_emo, W_sent, b_sent, outv);
}